// Round 6
// baseline (46957.565 us; speedup 1.0000x reference)
//
#include <hip/hip_runtime.h>

typedef _Float16 half2_t __attribute__((ext_vector_type(2)));
typedef unsigned int uint4_t __attribute__((ext_vector_type(4)));
typedef float float4_t __attribute__((ext_vector_type(4)));

#define T_STEPS 2048
#define NREGP   92     // f16 pairs of a W_hh row in VGPRs (184 elements)
#define NTAILD  36     // f16 pair-dwords of a row in LDS (72 elements)
#define TSTRIDE 36     // tail row stride in dwords (144B, 16B-aligned; 8/bank uniform)

// LDS map (bytes) — all 16B aligned
#define TAIL_OFF 0                    // 1024 rows * 144 B = 147456
#define X_OFF    147456               // 2048 f32          = 8192
#define HH_OFF   (X_OFF + 8192)       // 256 f16 h hi      = 512
#define HL_OFF   (HH_OFF + 512)       // 256 f16 h lo      = 512
#define EXCH_OFF (HL_OFF + 512)       // 256 f32 gi*gg     = 1024
#define R_OFF    (EXCH_OFF + 1024)    // 2*256 f32 fc part = 2048
#define SMEM_BYTES (R_OFF + 2048)     // 159744  (<= 163840)

__device__ __forceinline__ float fdot2(half2_t a, half2_t b, float c) {
#if __has_builtin(__builtin_amdgcn_fdot2)
    return __builtin_amdgcn_fdot2(a, b, c, false);
#else
    return c + (float)a[0] * (float)b[0] + (float)a[1] * (float)b[1];
#endif
}
__device__ __forceinline__ half2_t bch2(unsigned u) {
    return __builtin_bit_cast(half2_t, u);
}
__device__ __forceinline__ float rcp_fast(float x) {
#if __has_builtin(__builtin_amdgcn_rcpf)
    return __builtin_amdgcn_rcpf(x);
#else
    return 1.0f / x;
#endif
}
__device__ __forceinline__ float sigmoid_f(float x) {
    return rcp_fast(1.0f + __expf(-x));
}
__device__ __forceinline__ float tanh_f(float x) {
    return 1.0f - 2.0f * rcp_fast(__expf(2.0f * x) + 1.0f);
}

__global__ void
__launch_bounds__(512)
__attribute__((amdgpu_waves_per_eu(2, 2)))   // pin allocator: 2 waves/SIMD -> 256 VGPR budget
lstm_fused(
    const float* __restrict__ x,      // [128, 2048]
    const float* __restrict__ W_ih,   // [1024, 1]
    const float* __restrict__ W_hh,   // [1024, 256]
    const float* __restrict__ b_ih,   // [1024]
    const float* __restrict__ b_hh,   // [1024]
    const float* __restrict__ W_fc,   // [1, 256]
    const float* __restrict__ b_fc,   // [1]
    float* __restrict__ out)          // [128, 2048]
{
    extern __shared__ __align__(16) char smem[];
    unsigned*       tailp  = (unsigned*)(smem + TAIL_OFF);
    float*          x_lds  = (float*)(smem + X_OFF);
    unsigned short* hh_lds = (unsigned short*)(smem + HH_OFF);
    unsigned short* hl_lds = (unsigned short*)(smem + HL_OFF);
    float*          e_lds  = (float*)(smem + EXCH_OFF);
    float*          r_lds  = (float*)(smem + R_OFF);     // [2][256]

    const int tid   = threadIdx.x;        // 0..511
    const int b     = blockIdx.x;
    const int lane  = tid & 63;
    const int wave  = tid >> 6;
    const bool lower = (tid < 256);       // wave-uniform (waves 0-3)
    const int u     = lower ? tid : (tid - 256);   // hidden unit owned

    // rows: lower -> (u [i-gate], u+512 [g-gate]); upper -> (u+256 [f], u+768 [o])
    const int row0 = tid;                         // tid   (i or f row)
    const int row1 = tid + 512;                   // tid+512 (g or o row)

    // ---- preload x[b,:]
    for (int i = tid; i < T_STEPS; i += 512)
        x_lds[i] = x[b * T_STEPS + i];

    // ---- load + convert W rows: 92 f16-pairs to VGPRs, 36 pair-dwords to LDS tail
    half2_t w0[NREGP], w1[NREGP];
    {
        const float4_t* wr0 = (const float4_t*)(W_hh + row0 * 256);
        const float4_t* wr1 = (const float4_t*)(W_hh + row1 * 256);
        unsigned* t0 = tailp + row0 * TSTRIDE;
        unsigned* t1 = tailp + row1 * TSTRIDE;
        #pragma unroll
        for (int q = 0; q < 64; ++q) {
            float4_t v0 = wr0[q], v1 = wr1[q];
            half2_t a0 = { (_Float16)v0.x, (_Float16)v0.y };
            half2_t a1 = { (_Float16)v0.z, (_Float16)v0.w };
            half2_t c0 = { (_Float16)v1.x, (_Float16)v1.y };
            half2_t c1 = { (_Float16)v1.z, (_Float16)v1.w };
            const int pi = 2 * q;
            if (pi < NREGP)     { w0[pi] = a0; w1[pi] = c0; }
            else                { t0[pi - NREGP] = __builtin_bit_cast(unsigned, a0);
                                  t1[pi - NREGP] = __builtin_bit_cast(unsigned, c0); }
            if (pi + 1 < NREGP) { w0[pi + 1] = a1; w1[pi + 1] = c1; }
            else                { t0[pi + 1 - NREGP] = __builtin_bit_cast(unsigned, a1);
                                  t1[pi + 1 - NREGP] = __builtin_bit_cast(unsigned, c1); }
        }
    }

    const float wih0 = W_ih[row0], wih1 = W_ih[row1];
    const float bs0  = b_ih[row0] + b_hh[row0];
    const float bs1  = b_ih[row1] + b_hh[row1];
    const float wfc  = W_fc[u];          // used by upper only
    const float bfc  = b_fc[0];

    float c = 0.0f;                       // cell state, owned by upper threads
    if (lower) { hh_lds[u] = 0; hl_lds[u] = 0; }
    __syncthreads();

    const uint4_t*  hhq = (const uint4_t*)hh_lds;   // 32 chunks x 8 f16
    const uint4_t*  hlq = (const uint4_t*)hl_lds;
    const unsigned* t0p = tailp + row0 * TSTRIDE;
    const unsigned* t1p = tailp + row1 * TSTRIDE;

    #pragma unroll 1
    for (int t = 0; t < T_STEPS; ++t) {
        const int cur = t & 1, prev = cur ^ 1;
        const float xv = x_lds[t];

        // ---- phase A: preacts for both rows, h exact via hi+lo f16 split
        float s00 = fmaf(wih0, xv, bs0), s01 = 0.f, s02 = 0.f, s03 = 0.f;
        float s10 = fmaf(wih1, xv, bs1), s11 = 0.f, s12 = 0.f, s13 = 0.f;
        #pragma unroll
        for (int cc = 0; cc < 23; ++cc) {          // 92 VGPR-resident pairs
            uint4_t h4 = hhq[cc], l4 = hlq[cc];
            s00 = fdot2(w0[4*cc+0], bch2(h4.x), s00);
            s01 = fdot2(w0[4*cc+1], bch2(h4.y), s01);
            s00 = fdot2(w0[4*cc+2], bch2(h4.z), s00);
            s01 = fdot2(w0[4*cc+3], bch2(h4.w), s01);
            s02 = fdot2(w0[4*cc+0], bch2(l4.x), s02);
            s03 = fdot2(w0[4*cc+1], bch2(l4.y), s03);
            s02 = fdot2(w0[4*cc+2], bch2(l4.z), s02);
            s03 = fdot2(w0[4*cc+3], bch2(l4.w), s03);
            s10 = fdot2(w1[4*cc+0], bch2(h4.x), s10);
            s11 = fdot2(w1[4*cc+1], bch2(h4.y), s11);
            s10 = fdot2(w1[4*cc+2], bch2(h4.z), s10);
            s11 = fdot2(w1[4*cc+3], bch2(h4.w), s11);
            s12 = fdot2(w1[4*cc+0], bch2(l4.x), s12);
            s13 = fdot2(w1[4*cc+1], bch2(l4.y), s13);
            s12 = fdot2(w1[4*cc+2], bch2(l4.z), s12);
            s13 = fdot2(w1[4*cc+3], bch2(l4.w), s13);
        }
        #pragma unroll
        for (int cc = 23; cc < 32; ++cc) {         // 36 LDS-tail pair-dwords
            uint4_t h4 = hhq[cc], l4 = hlq[cc];
            uint4_t wa = *(const uint4_t*)(t0p + (cc - 23) * 4);
            uint4_t wb = *(const uint4_t*)(t1p + (cc - 23) * 4);
            s00 = fdot2(bch2(wa.x), bch2(h4.x), s00);
            s01 = fdot2(bch2(wa.y), bch2(h4.y), s01);
            s00 = fdot2(bch2(wa.z), bch2(h4.z), s00);
            s01 = fdot2(bch2(wa.w), bch2(h4.w), s01);
            s02 = fdot2(bch2(wa.x), bch2(l4.x), s02);
            s03 = fdot2(bch2(wa.y), bch2(l4.y), s03);
            s02 = fdot2(bch2(wa.z), bch2(l4.z), s02);
            s03 = fdot2(bch2(wa.w), bch2(l4.w), s03);
            s10 = fdot2(bch2(wb.x), bch2(h4.x), s10);
            s11 = fdot2(bch2(wb.y), bch2(h4.y), s11);
            s10 = fdot2(bch2(wb.z), bch2(h4.z), s10);
            s11 = fdot2(bch2(wb.w), bch2(h4.w), s11);
            s12 = fdot2(bch2(wb.x), bch2(l4.x), s12);
            s13 = fdot2(bch2(wb.y), bch2(l4.y), s13);
            s12 = fdot2(bch2(wb.z), bch2(l4.z), s12);
            s13 = fdot2(bch2(wb.w), bch2(l4.w), s13);
        }
        const float p0 = (s00 + s01) + (s02 + s03);   // i or f preact
        const float p1 = (s10 + s11) + (s12 + s13);   // g or o preact

        float gA, gB;
        if (lower) {                       // i, g
            gA = sigmoid_f(p0);
            gB = tanh_f(p1);
            e_lds[u] = gA * gB;            // gi * gg
        } else {                           // f, o
            gA = sigmoid_f(p0);            // gf
            gB = sigmoid_f(p1);            // go
        }
        __syncthreads();                   // B1: gi*gg visible

        if (!lower) {
            // ---- phase B: cell/hidden update (upper threads own unit u)
            c = fmaf(gA, c, e_lds[u]);
            const float h  = gB * tanh_f(c);
            const _Float16 hh = (_Float16)h;
            const _Float16 hl = (_Float16)(h - (float)hh);
            hh_lds[u] = __builtin_bit_cast(unsigned short, hh);
            hl_lds[u] = __builtin_bit_cast(unsigned short, hl);
            r_lds[cur * 256 + u] = h * wfc;
        } else if (t && wave == (t & 3)) {
            // ---- fused FC for step t-1 (lower rot wave; overlaps phase B)
            float4_t rv = *(const float4_t*)(r_lds + prev * 256 + lane * 4);
            float s = (rv.x + rv.y) + (rv.z + rv.w);
            #pragma unroll
            for (int k = 32; k >= 1; k >>= 1) s += __shfl_xor(s, k);
            if (lane == 0) out[b * T_STEPS + (t - 1)] = sigmoid_f(s + bfc);
        }
        __syncthreads();                   // B2: h ready for next step
    }

    // final FC for t = T-1 (r buffer (T-1)&1 = 1)
    if (wave == 0) {
        float4_t rv = *(const float4_t*)(r_lds + 256 + lane * 4);
        float s = (rv.x + rv.y) + (rv.z + rv.w);
        #pragma unroll
        for (int k = 32; k >= 1; k >>= 1) s += __shfl_xor(s, k);
        if (lane == 0) out[b * T_STEPS + (T_STEPS - 1)] = sigmoid_f(s + bfc);
    }
}

extern "C" void kernel_launch(void* const* d_in, const int* in_sizes, int n_in,
                              void* d_out, int out_size, void* d_ws, size_t ws_size,
                              hipStream_t stream) {
    (void)in_sizes; (void)n_in; (void)d_ws; (void)ws_size; (void)out_size;
    const float* x    = (const float*)d_in[0];
    const float* W_ih = (const float*)d_in[1];
    const float* W_hh = (const float*)d_in[2];
    const float* b_ih = (const float*)d_in[3];
    const float* b_hh = (const float*)d_in[4];
    const float* W_fc = (const float*)d_in[5];
    const float* b_fc = (const float*)d_in[6];

    hipFuncSetAttribute(reinterpret_cast<const void*>(lstm_fused),
                        hipFuncAttributeMaxDynamicSharedMemorySize, SMEM_BYTES);
    lstm_fused<<<dim3(128), dim3(512), SMEM_BYTES, stream>>>(
        x, W_ih, W_hh, b_ih, b_hh, W_fc, b_fc, (float*)d_out);
}

// Round 8
// 35886.243 us; speedup vs baseline: 1.3085x; 1.3085x over previous
//
#include <hip/hip_runtime.h>

typedef _Float16 half2_t __attribute__((ext_vector_type(2)));
typedef unsigned int uint4_t __attribute__((ext_vector_type(4)));
typedef float float4_t __attribute__((ext_vector_type(4)));

#define T_STEPS   2048
#define NREG      64          // own-half f16 pairs in VGPRs
#define TSTRIDE   72          // LDS tail row stride in dwords (288B, 16B-aligned)
#define FLAG_BASE 0x13570000u // poison-proof flag values (!= 0xAAAAAAAA)

// LDS map (bytes)
#define TAIL_OFF 0                      // 512 rows * 288 B = 147456
#define X_OFF    147456                 // 2048 f32 x[b,:]  = 8192
#define OH_OFF   (X_OFF + 8192)         // own h packed: hi[128 f16] lo[128 f16] = 512
#define HF_OFF   (OH_OFF + 512)         // h f32, 2 buffers * 128 = 1024
#define G_OFF    (HF_OFF + 1024)        // 512 f32 gate activations = 2048
#define SMEM_BYTES (G_OFF + 2048)       // 159232 (<= 163840)

// d_ws dword layout: flags spread 128B apart; pub: 2 slots * 128 dw per block
#define WS_FLAG_STRIDE 32
#define WS_PUB_BASE    8192
#define WS_PUB_STRIDE  256

__device__ __forceinline__ float fdot2(half2_t a, half2_t b, float c) {
#if __has_builtin(__builtin_amdgcn_fdot2)
    return __builtin_amdgcn_fdot2(a, b, c, false);
#else
    return c + (float)a[0] * (float)b[0] + (float)a[1] * (float)b[1];
#endif
}
__device__ __forceinline__ half2_t bch2(unsigned u) { return __builtin_bit_cast(half2_t, u); }
__device__ __forceinline__ unsigned short f16b(_Float16 h) { return __builtin_bit_cast(unsigned short, h); }
__device__ __forceinline__ float f16f(unsigned short u) { return (float)__builtin_bit_cast(_Float16, u); }
__device__ __forceinline__ float rcp_fast(float x) {
#if __has_builtin(__builtin_amdgcn_rcpf)
    return __builtin_amdgcn_rcpf(x);
#else
    return 1.0f / x;
#endif
}
__device__ __forceinline__ float sigmoid_f(float x) { return rcp_fast(1.0f + __expf(-x)); }
__device__ __forceinline__ float tanh_f(float x) { return 1.0f - 2.0f * rcp_fast(__expf(2.0f * x) + 1.0f); }

__global__ void __launch_bounds__(512)
lstm_pair(const float* __restrict__ x,      // [128, 2048]
          const float* __restrict__ W_ih,   // [1024, 1]
          const float* __restrict__ W_hh,   // [1024, 256]
          const float* __restrict__ b_ih,   // [1024]
          const float* __restrict__ b_hh,   // [1024]
          const float* __restrict__ W_fc,   // [1, 256]
          const float* __restrict__ b_fc,   // [1]
          float* __restrict__ out,          // [128, 2048]
          unsigned* __restrict__ ws)
{
    extern __shared__ __align__(16) char smem[];
    unsigned* tailp = (unsigned*)(smem + TAIL_OFF);
    float*    x_lds = (float*)(smem + X_OFF);
    unsigned* own_h = (unsigned*)(smem + OH_OFF);   // hi halfwords [0,128), lo [128,256)
    float*    h_f32 = (float*)(smem + HF_OFF);      // [2][128]
    float*    g_lds = (float*)(smem + G_OFF);       // [4][128] = g_lds[tid]

    const int tid  = threadIdx.x;        // 0..511
    const int blk  = blockIdx.x;         // 0..255
    const int b    = blk & 127;          // batch row
    const int p    = blk >> 7;           // half: units [p*128, p*128+128)
    const int part = blk ^ 128;          // partner block (same XCD under %8 round-robin)
    const int lane = tid & 63;
    const int wave = tid >> 6;
    const int g    = tid >> 7;           // gate 0..3 = i,f,g,o (wave-uniform)
    const int j    = tid & 127;          // unit within half
    const int row  = g * 256 + p * 128 + j;   // W_hh gate row owned by this thread

    unsigned* flag_me = ws + (unsigned)blk  * WS_FLAG_STRIDE;
    unsigned* flag_pa = ws + (unsigned)part * WS_FLAG_STRIDE;
    unsigned* pub_me  = ws + WS_PUB_BASE + (unsigned)blk  * WS_PUB_STRIDE;
    unsigned* pub_pa  = ws + WS_PUB_BASE + (unsigned)part * WS_PUB_STRIDE;

    // ---- preload x[b,:]
    for (int i = tid; i < T_STEPS; i += 512)
        x_lds[i] = x[b * T_STEPS + i];

    // ---- W row: own-half columns -> 64 f16 pairs in VGPRs; remote-half -> LDS tail
    half2_t w_own[NREG];
    {
        const float4_t* wo = (const float4_t*)(W_hh + row * 256 + p * 128);
        const float4_t* wr = (const float4_t*)(W_hh + row * 256 + (1 - p) * 128);
        unsigned* tw = tailp + tid * TSTRIDE;
        #pragma unroll
        for (int q = 0; q < 32; ++q) {
            float4_t v = wo[q];
            w_own[2*q]   = half2_t{ (_Float16)v.x, (_Float16)v.y };
            w_own[2*q+1] = half2_t{ (_Float16)v.z, (_Float16)v.w };
        }
        #pragma unroll
        for (int q = 0; q < 32; ++q) {
            float4_t v = wr[q];
            half2_t p0 = { (_Float16)v.x, (_Float16)v.y };
            half2_t p1 = { (_Float16)v.z, (_Float16)v.w };
            tw[2*q]   = __builtin_bit_cast(unsigned, p0);
            tw[2*q+1] = __builtin_bit_cast(unsigned, p1);
        }
    }

    const float wih  = W_ih[row];
    const float bsum = b_ih[row] + b_hh[row];
    const float bfc  = b_fc[0];

    float c = 0.0f;                      // cell state (threads tid<128, unit j)
    if (tid < 128) own_h[tid] = 0u;      // h_0 = 0 (hi+lo halves)
    __syncthreads();

    #pragma unroll 1
    for (int t = 0; t < T_STEPS; ++t) {
        // ---- A1: own-half dot (regs x LDS-broadcast h), h exact via hi+lo f16
        float a0 = fmaf(wih, x_lds[t], bsum), a1 = 0.f, a2 = 0.f, a3 = 0.f;
        {
            const uint4_t* oh = (const uint4_t*)own_h;   // [0..15]=hi, [16..31]=lo
            #pragma unroll
            for (int m = 0; m < 16; ++m) {
                uint4_t h4 = oh[m], l4 = oh[16 + m];
                a0 = fdot2(w_own[4*m+0], bch2(h4.x), a0);
                a1 = fdot2(w_own[4*m+1], bch2(h4.y), a1);
                a0 = fdot2(w_own[4*m+2], bch2(h4.z), a0);
                a1 = fdot2(w_own[4*m+3], bch2(h4.w), a1);
                a2 = fdot2(w_own[4*m+0], bch2(l4.x), a2);
                a3 = fdot2(w_own[4*m+1], bch2(l4.y), a3);
                a2 = fdot2(w_own[4*m+2], bch2(l4.z), a2);
                a3 = fdot2(w_own[4*m+3], bch2(l4.w), a3);
            }
        }
        // ---- A2: wait partner h_t, remote-half dot (LDS tail W x L1/L2-broadcast h)
        if (t > 0) {
            const unsigned want = FLAG_BASE + (unsigned)t;
            while (__hip_atomic_load(flag_pa, __ATOMIC_RELAXED, __HIP_MEMORY_SCOPE_AGENT) != want) {}
            __builtin_amdgcn_fence(__ATOMIC_ACQUIRE, "agent");
            const uint4_t* rh = (const uint4_t*)(pub_pa + (t & 1) * 128);
            const uint4_t* tw = (const uint4_t*)(tailp + tid * TSTRIDE);
            #pragma unroll
            for (int m = 0; m < 16; ++m) {
                uint4_t h4 = rh[m], l4 = rh[16 + m];
                uint4_t w4 = tw[m];
                a0 = fdot2(bch2(w4.x), bch2(h4.x), a0);
                a1 = fdot2(bch2(w4.y), bch2(h4.y), a1);
                a0 = fdot2(bch2(w4.z), bch2(h4.z), a0);
                a1 = fdot2(bch2(w4.w), bch2(h4.w), a1);
                a2 = fdot2(bch2(w4.x), bch2(l4.x), a2);
                a3 = fdot2(bch2(w4.y), bch2(l4.y), a3);
                a2 = fdot2(bch2(w4.z), bch2(l4.z), a2);
                a3 = fdot2(bch2(w4.w), bch2(l4.w), a3);
            }
        }
        const float preact = (a0 + a1) + (a2 + a3);
        g_lds[tid] = (g == 2) ? tanh_f(preact) : sigmoid_f(preact);
        __syncthreads();                   // B1: all 4 gates of my half ready

        if (tid < 128) {
            // ---- B: cell/hidden update for unit j; stage + publish h_{t+1}
            const float gi = g_lds[j], gf = g_lds[128 + j];
            const float gg = g_lds[256 + j], go = g_lds[384 + j];
            c = fmaf(gf, c, gi * gg);
            const float h = go * tanh_f(c);
            const _Float16 hh = (_Float16)h;
            const _Float16 hl = (_Float16)(h - (float)hh);
            const int s = (t + 1) & 1;
            ((unsigned short*)own_h)[j]       = f16b(hh);
            ((unsigned short*)own_h)[128 + j] = f16b(hl);
            h_f32[s * 128 + j] = h;
            unsigned short* pb = (unsigned short*)(pub_me + s * 128);
            pb[j]       = f16b(hh);
            pb[128 + j] = f16b(hl);
        } else if (p == 0 && t > 0 && wave == 2 + ((t - 1) % 6)) {
            // ---- FC for out[t-1] using h_t (rot wave; overlaps phase B)
            const int s = t & 1;
            const unsigned short* rp = (const unsigned short*)(pub_pa + s * 128);
            float sacc = h_f32[s * 128 + lane]      * W_fc[lane]
                       + h_f32[s * 128 + 64 + lane] * W_fc[64 + lane]
                       + (f16f(rp[lane])      + f16f(rp[128 + lane])) * W_fc[128 + lane]
                       + (f16f(rp[64 + lane]) + f16f(rp[192 + lane])) * W_fc[192 + lane];
            #pragma unroll
            for (int k = 32; k >= 1; k >>= 1) sacc += __shfl_xor(sacc, k);
            if (lane == 0) out[b * T_STEPS + (t - 1)] = sigmoid_f(sacc + bfc);
        }
        __syncthreads();                   // B2: h_{t+1} + pub stores drained
        if (tid == 0) {
            __builtin_amdgcn_fence(__ATOMIC_RELEASE, "agent");
            __hip_atomic_store(flag_me, FLAG_BASE + (unsigned)(t + 1),
                               __ATOMIC_RELAXED, __HIP_MEMORY_SCOPE_AGENT);
        }
    }

    // ---- final FC: out[T-1] from h_T (p==0, wave 0)
    if (p == 0 && wave == 0) {
        const unsigned want = FLAG_BASE + (unsigned)T_STEPS;
        while (__hip_atomic_load(flag_pa, __ATOMIC_RELAXED, __HIP_MEMORY_SCOPE_AGENT) != want) {}
        __builtin_amdgcn_fence(__ATOMIC_ACQUIRE, "agent");
        const int s = T_STEPS & 1;         // = 0
        const unsigned short* rp = (const unsigned short*)(pub_pa + s * 128);
        float sacc = h_f32[s * 128 + lane]      * W_fc[lane]
                   + h_f32[s * 128 + 64 + lane] * W_fc[64 + lane]
                   + (f16f(rp[lane])      + f16f(rp[128 + lane])) * W_fc[128 + lane]
                   + (f16f(rp[64 + lane]) + f16f(rp[192 + lane])) * W_fc[192 + lane];
        #pragma unroll
        for (int k = 32; k >= 1; k >>= 1) sacc += __shfl_xor(sacc, k);
        if (lane == 0) out[b * T_STEPS + (T_STEPS - 1)] = sigmoid_f(sacc + bfc);
    }
}

extern "C" void kernel_launch(void* const* d_in, const int* in_sizes, int n_in,
                              void* d_out, int out_size, void* d_ws, size_t ws_size,
                              hipStream_t stream) {
    (void)in_sizes; (void)n_in; (void)ws_size; (void)out_size;
    const float* x    = (const float*)d_in[0];
    const float* W_ih = (const float*)d_in[1];
    const float* W_hh = (const float*)d_in[2];
    const float* b_ih = (const float*)d_in[3];
    const float* b_hh = (const float*)d_in[4];
    const float* W_fc = (const float*)d_in[5];
    const float* b_fc = (const float*)d_in[6];

    hipFuncSetAttribute(reinterpret_cast<const void*>(lstm_pair),
                        hipFuncAttributeMaxDynamicSharedMemorySize, SMEM_BYTES);
    lstm_pair<<<dim3(256), dim3(512), SMEM_BYTES, stream>>>(
        x, W_ih, W_hh, b_ih, b_hh, W_fc, b_fc, (float*)d_out, (unsigned*)d_ws);
}